// Round 11
// baseline (1927.044 us; speedup 1.0000x reference)
//
#include <hip/hip_runtime.h>
#include <hip/hip_bf16.h>
#include <math.h>

// Problem constants
#define B_  16
#define S_  1000
#define IN_ 32
#define D_  512
#define H_  8
#define FF_ 2048
#define L_  6
#define DK_ 64
#define M_  (B_ * S_)   // 16000 rows
#define SP_ 1024        // padded sequence stride for V^T

typedef __bf16 bf16x8 __attribute__((ext_vector_type(8)));
typedef float  floatx4 __attribute__((ext_vector_type(4)));

#define FLAG_RELU 1
#define FLAG_BF16 2
#define FLAG_QKV  4

// softmax scale folded into Wq/bq at prep: 0.125 * log2(e)
#define QSCALE 0.18033688011112042f

// ============ bf16 MFMA GEMM: C[M,N] = act(A[M,K] @ B[K,N] + bias) ============
// A: bf16 [M][K] row-major. BT: bf16 [N][K] row-major. 128x128 tile, BK=32,
// 256 threads = 4 waves (64x64/wave via 4x4 of 16x16x32 MFMA).
// v13 = v12 K-loop exactly (1-deep reg-prefetch + dbuf LDS + XCD swizzle,
// unpadded 32-elem LDS rows) with SWAPPED MFMA operands: acc = mfma(bf, af)
// computes the transposed C-block, so each lane holds 4 CONSECUTIVE COLS
// (n = ...+lq*4+r) at fixed row (m = ...+lm). Epilogue stores collapse from
// 64 scalar bf16 to 16 uint2 / 16 float4 per thread; bias loads become one
// float4 per j. K-loop instruction stream unchanged.
// FLAG_QKV: N=1536; epilogue routes n<512 -> q, <1024 -> k, else transposed V^T.
__global__ __launch_bounds__(256) void gemm_mfma(
    const __bf16* __restrict__ A, const __bf16* __restrict__ BT,
    const float* __restrict__ bias, void* __restrict__ C,
    int M, int N, int K, int flags)
{
    __shared__ __bf16 Asm[2][128 * 32];
    __shared__ __bf16 Bsm[2][128 * 32];

    int tid  = threadIdx.x;
    int wave = tid >> 6;
    int lane = tid & 63;

    // bijective chunked XCD swizzle (m204): orig%8 ~ hardware XCD; give each
    // XCD a contiguous chunk of the x-fastest linear id so same-row blocks
    // (sharing the A-panel) land on one XCD's L2.
    int gx = gridDim.x, nwg = gx * (int)gridDim.y;
    int orig = blockIdx.y * gx + blockIdx.x;
    int qq = nwg >> 3, rr = nwg & 7;
    int xcd = orig & 7, loc = orig >> 3;
    int nid = (xcd < rr ? xcd * (qq + 1) : rr * (qq + 1) + (xcd - rr) * qq) + loc;
    int bm = (nid / gx) * 128;
    int bn = (nid % gx) * 128;

    int wm = (wave & 1) * 64;
    int wn = (wave >> 1) * 64;
    int lm = lane & 15;
    int lq = lane >> 4;

    floatx4 acc[4][4] = {};

    // staging geometry: thread stages A/B rows crow, crow+64, 16B chunk cpart
    int crow  = tid >> 2;
    int cpart = (tid & 3) * 8;
    const __bf16* ag0 = A + (size_t)(bm + crow) * K + cpart;
    const __bf16* ag1 = A + (size_t)(bm + 64 + crow) * K + cpart;
    int nr0 = bn + crow, nr1 = bn + 64 + crow;
    const __bf16* bg0 = BT + (size_t)nr0 * K + cpart;
    const __bf16* bg1 = BT + (size_t)nr1 * K + cpart;
    bool bv0 = nr0 < N, bv1 = nr1 < N;

    // ---- prologue: load tile 0 into prefetch regs ----
    uint4 pa0, pa1, pb0, pb1;
    pa0 = *(const uint4*)ag0;
    pa1 = *(const uint4*)ag1;
    pb0 = bv0 ? *(const uint4*)bg0 : make_uint4(0, 0, 0, 0);
    pb1 = bv1 ? *(const uint4*)bg1 : make_uint4(0, 0, 0, 0);

    for (int k0 = 0, it = 0; k0 < K; k0 += 32, ++it) {
        const int cur = it & 1;
        // write prefetched tile (readers of this buffer finished before the
        // previous barrier -> single-barrier double-buffer is race-free)
        *(uint4*)&Asm[cur][tid * 8]        = pa0;
        *(uint4*)&Asm[cur][2048 + tid * 8] = pa1;
        *(uint4*)&Bsm[cur][tid * 8]        = pb0;
        *(uint4*)&Bsm[cur][2048 + tid * 8] = pb1;
        __syncthreads();

        // issue next tile's loads; they fly during compute below
        if (k0 + 32 < K) {
            pa0 = *(const uint4*)(ag0 + k0 + 32);
            pa1 = *(const uint4*)(ag1 + k0 + 32);
            pb0 = bv0 ? *(const uint4*)(bg0 + k0 + 32) : make_uint4(0, 0, 0, 0);
            pb1 = bv1 ? *(const uint4*)(bg1 + k0 + 32) : make_uint4(0, 0, 0, 0);
        }

        bf16x8 af[4], bf[4];
        #pragma unroll
        for (int i = 0; i < 4; ++i) {
            af[i] = *(const bf16x8*)&Asm[cur][(wm + i * 16 + lm) * 32 + lq * 8];
            bf[i] = *(const bf16x8*)&Bsm[cur][(wn + i * 16 + lm) * 32 + lq * 8];
        }
        // SWAPPED operands: D-block = C^T; lane holds n = lq*4+r, m = lm.
        #pragma unroll
        for (int i = 0; i < 4; ++i)
            #pragma unroll
            for (int j = 0; j < 4; ++j)
                acc[i][j] = __builtin_amdgcn_mfma_f32_16x16x32_bf16(
                    bf[j], af[i], acc[i][j], 0, 0, 0);
    }

    if (flags & FLAG_QKV) {
        int sec = bn >> 9;
        if (sec < 2) {
            __bf16* dst = (__bf16*)C + (sec ? (size_t)8192000 : 0);
            #pragma unroll
            for (int i = 0; i < 4; ++i) {
                int m = bm + wm + i * 16 + lm;
                #pragma unroll
                for (int j = 0; j < 4; ++j) {
                    int cb = bn + wn + j * 16 + lq * 4;
                    float4 b4 = *(const float4*)&bias[cb];
                    union { unsigned short u[4]; uint2 w; } pk;
                    union { __bf16 h; unsigned short u; } cv;
                    cv.h = (__bf16)(acc[i][j][0] + b4.x); pk.u[0] = cv.u;
                    cv.h = (__bf16)(acc[i][j][1] + b4.y); pk.u[1] = cv.u;
                    cv.h = (__bf16)(acc[i][j][2] + b4.z); pk.u[2] = cv.u;
                    cv.h = (__bf16)(acc[i][j][3] + b4.w); pk.u[3] = cv.u;
                    *(uint2*)&dst[(size_t)m * 512 + (cb & 511)] = pk.w;
                }
            }
        } else {
            __bf16* vt = (__bf16*)C + (size_t)16384000;
            #pragma unroll
            for (int i = 0; i < 4; ++i) {
                int m = bm + wm + i * 16 + lm;
                int bbq = m / 1000;
                int s0  = m - bbq * 1000;
                #pragma unroll
                for (int j = 0; j < 4; ++j) {
                    int cb = bn + wn + j * 16 + lq * 4;
                    int col = cb & 511;
                    int head = col >> 6, dk = col & 63;  // dk window 4-aligned -> head const
                    float4 b4 = *(const float4*)&bias[cb];
                    __bf16* vp = vt + ((size_t)(bbq * H_ + head) * DK_ + dk) * SP_ + s0;
                    vp[0 * SP_] = (__bf16)(acc[i][j][0] + b4.x);
                    vp[1 * SP_] = (__bf16)(acc[i][j][1] + b4.y);
                    vp[2 * SP_] = (__bf16)(acc[i][j][2] + b4.z);
                    vp[3 * SP_] = (__bf16)(acc[i][j][3] + b4.w);
                }
            }
        }
        return;
    }

    #pragma unroll
    for (int i = 0; i < 4; ++i) {
        int m = bm + wm + i * 16 + lm;
        #pragma unroll
        for (int j = 0; j < 4; ++j) {
            int n0 = bn + wn + j * 16 + lq * 4;
            if (n0 >= N) continue;            // N % 4 == 0 always -> full windows
            float4 b4 = *(const float4*)&bias[n0];
            float v0 = acc[i][j][0] + b4.x;
            float v1 = acc[i][j][1] + b4.y;
            float v2 = acc[i][j][2] + b4.z;
            float v3 = acc[i][j][3] + b4.w;
            if (flags & FLAG_RELU) {
                v0 = fmaxf(v0, 0.f); v1 = fmaxf(v1, 0.f);
                v2 = fmaxf(v2, 0.f); v3 = fmaxf(v3, 0.f);
            }
            if (flags & FLAG_BF16) {
                union { unsigned short u[4]; uint2 w; } pk;
                union { __bf16 h; unsigned short u; } cv;
                cv.h = (__bf16)v0; pk.u[0] = cv.u;
                cv.h = (__bf16)v1; pk.u[1] = cv.u;
                cv.h = (__bf16)v2; pk.u[2] = cv.u;
                cv.h = (__bf16)v3; pk.u[3] = cv.u;
                *(uint2*)&((__bf16*)C)[(size_t)m * N + n0] = pk.w;
            } else {
                *(float4*)&((float*)C)[(size_t)m * N + n0] = make_float4(v0, v1, v2, v3);
            }
        }
    }
}

// ---------------- shared 32x32 transpose helper ----------------
__device__ __forceinline__ void trans_tile(
    const float* __restrict__ src, __bf16* __restrict__ dst,
    int K, int N, float scale, int tx0, int ty0)
{
    __shared__ float t[32][33];
    int n0 = tx0 * 32, k0 = ty0 * 32;
    int tx = threadIdx.x & 31, ty = threadIdx.x >> 5;   // 32 x 8
    #pragma unroll
    for (int i = 0; i < 32; i += 8) {
        int k = k0 + ty + i, n = n0 + tx;
        t[ty + i][tx] = (k < K && n < N) ? src[(size_t)k * N + n] * scale : 0.f;
    }
    __syncthreads();
    #pragma unroll
    for (int i = 0; i < 32; i += 8) {
        int n = n0 + ty + i, k = k0 + tx;
        if (n < N && k < K) dst[(size_t)n * K + k] = (__bf16)t[tx][ty + i];
    }
}

// ---- merged QKVO weight prep: z = l*4 + {0:q,1:k,2:v,3:o}, all 512x512 ----
__global__ __launch_bounds__(256) void transpose_qkvo(
    const float* __restrict__ Wq, const float* __restrict__ Wk,
    const float* __restrict__ Wv, const float* __restrict__ Wo,
    __bf16* __restrict__ WqkvT, __bf16* __restrict__ WoT)
{
    int l = blockIdx.z >> 2, which = blockIdx.z & 3;
    const float* src; __bf16* dst; float sc = 1.f;
    size_t so = (size_t)l * 512 * 512;
    if (which == 0)      { src = Wq + so; dst = WqkvT + (size_t)l * 1536 * 512; sc = QSCALE; }
    else if (which == 1) { src = Wk + so; dst = WqkvT + (size_t)l * 1536 * 512 + 512 * 512; }
    else if (which == 2) { src = Wv + so; dst = WqkvT + (size_t)l * 1536 * 512 + 1024 * 512; }
    else                 { src = Wo + so; dst = WoT + so; }
    trans_tile(src, dst, 512, 512, sc, blockIdx.x, blockIdx.y);
}

// ---- merged FFN weight prep: z = l*2 + {0:W1 (512x2048), 1:W2 (2048x512)} ----
__global__ __launch_bounds__(256) void transpose_ffn(
    const float* __restrict__ W1, const float* __restrict__ W2,
    __bf16* __restrict__ W1T, __bf16* __restrict__ W2T)
{
    int l = blockIdx.z >> 1, which = blockIdx.z & 1;
    size_t so = (size_t)l * 512 * 2048;
    int K = which ? 2048 : 512, N = which ? 512 : 2048;
    if ((int)blockIdx.x >= N / 32 || (int)blockIdx.y >= K / 32) return;
    trans_tile((which ? W2 : W1) + so, (which ? W2T : W1T) + so,
               K, N, 1.f, blockIdx.x, blockIdx.y);
}

// ---- merged misc weight prep via descriptor array ----
struct TDesc { const float* src; __bf16* dst; int K; int N; float scale; };
struct TDescArr { TDesc d[7]; };

__global__ __launch_bounds__(256) void transpose_misc(TDescArr ds)
{
    TDesc t = ds.d[blockIdx.z];
    if ((int)blockIdx.x * 32 >= t.N || (int)blockIdx.y * 32 >= t.K) return;
    trans_tile(t.src, t.dst, t.K, t.N, t.scale, blockIdx.x, blockIdx.y);
}

// ---------------- fp32 -> bf16 cast ----------------
__global__ void cast_bf16(const float* __restrict__ src, __bf16* __restrict__ dst, int n)
{
    int i = blockIdx.x * 256 + threadIdx.x;
    if (i < n) dst[i] = (__bf16)src[i];
}

// ---------------- concat q/k/v biases into [L][1536]; bq scaled ----------------
__global__ void concat_bias(const float* __restrict__ bq, const float* __restrict__ bk,
                            const float* __restrict__ bv, float* __restrict__ dst)
{
    int i = blockIdx.x * 256 + threadIdx.x;
    if (i >= L_ * 1536) return;
    int l = i / 1536, j = i - l * 1536;
    float v = (j < 512) ? bq[l * 512 + j] * QSCALE
            : (j < 1024) ? bk[l * 512 + j - 512]
                         : bv[l * 512 + j - 1024];
    dst[i] = v;
}

// ---------------- positional encoding add (writes fp32 + bf16) ----------------
__global__ void add_pos_kernel(float* __restrict__ h, __bf16* __restrict__ hb)
{
    int idx = blockIdx.x * 256 + threadIdx.x;
    if (idx >= B_ * S_ * D_) return;
    int d = idx % D_;
    int s = (idx / D_) % S_;
    int two_i = d & ~1;
    float ang = (float)s * expf((float)two_i * (-9.210340371976184f / (float)D_));
    float v = h[idx] + ((d & 1) ? cosf(ang) : sinf(ang));
    h[idx] = v;
    hb[idx] = (__bf16)v;
}

// ============ MFMA flash attention v7 (unchanged from round 5's best) ============
#define AST 72   // LDS row stride in bf16 (144 B, 16B-aligned)

__global__ __launch_bounds__(256) void attn_mfma(
    const __bf16* __restrict__ q, const __bf16* __restrict__ k,
    const __bf16* __restrict__ vt, __bf16* __restrict__ ctx)
{
    // chunked XCD swizzle over 1024 blocks (1024 % 8 == 0 -> bijective)
    const int id = blockIdx.x;
    const int w  = (id & 7) * 128 + (id >> 3);
    const int qt = w & 7, hh = (w >> 3) & 7, bb = w >> 6;

    const int tid = threadIdx.x;
    const int wave = tid >> 6, lane = tid & 63;
    const int lm = lane & 15, lq = lane >> 4;

    __shared__ __bf16 Ks[64 * AST];
    __shared__ __bf16 Vt[64 * AST];

    const size_t headbase = (size_t)bb * S_ * D_ + hh * DK_;
    const __bf16* kbase  = k + headbase;
    const __bf16* vtbase = vt + (size_t)(bb * H_ + hh) * DK_ * SP_;

    // ---- Q fragments straight from global (B operand of swapped QK^T) ----
    bf16x8 af[2][2] = {};
    #pragma unroll
    for (int iq = 0; iq < 2; ++iq) {
        int qrow = qt * 128 + wave * 32 + iq * 16 + lm;
        if (qrow < S_) {
            const __bf16* qp = q + headbase + (size_t)qrow * D_;
            af[iq][0] = *(const bf16x8*)(qp + lq * 8);
            af[iq][1] = *(const bf16x8*)(qp + 32 + lq * 8);
        }
    }

    floatx4 oacc[2][4] = {};
    floatx4 lacc[2] = {};          // row-sum accumulators via ones-MFMA

    bf16x8 ones8;
    #pragma unroll
    for (int j = 0; j < 8; ++j) ones8[j] = (__bf16)1.f;

    // staging geometry (invariant): thread stages rows sr, sr+32, 16B chunk sc8
    const int sr  = tid >> 3;
    const int sc8 = (tid & 7) * 8;
    // inverse bit-permutation for V columns: group base T -> LDS col
    // c = T5*32 + T3*16 + T2*8 + T4*4   (low 2 bits pass through)
    const int colA = (sc8 & 32) | ((sc8 & 8) << 1) | ((sc8 & 16) >> 2);

    // ---- prologue: load tile 0 into regs ----
    uint4 ku[2], vu[2];
    #pragma unroll
    for (int i = 0; i < 2; ++i) {
        int r = sr + i * 32;
        ku[i] = *(const uint4*)(kbase + (size_t)r * D_ + sc8);
        vu[i] = *(const uint4*)(vtbase + (size_t)r * SP_ + sc8);
    }

    for (int jt = 0; jt < 16; ++jt) {
        const int t0 = jt * 64;
        const bool tail = (jt == 15);

        __syncthreads();   // all waves done reading Ks/Vt of previous tile
        #pragma unroll
        for (int i = 0; i < 2; ++i) {
            int r = sr + i * 32;
            *(uint4*)&Ks[r * AST + sc8] = ku[i];
            uint2 vlo = make_uint2(vu[i].x, vu[i].y);   // t_local sc8..sc8+3
            uint2 vhi = make_uint2(vu[i].z, vu[i].w);   // t_local sc8+4..sc8+7
            *(uint2*)&Vt[r * AST + colA]     = vlo;
            *(uint2*)&Vt[r * AST + colA + 8] = vhi;
        }
        __syncthreads();

        // ---- issue next tile's loads; they fly during compute below ----
        if (jt < 15) {
            int t0n = t0 + 64;
            #pragma unroll
            for (int i = 0; i < 2; ++i) {
                int r = sr + i * 32;
                int trow = t0n + r;
                ku[i] = (trow < S_) ? *(const uint4*)(kbase + (size_t)trow * D_ + sc8)
                                    : make_uint4(0, 0, 0, 0);
                vu[i] = *(const uint4*)(vtbase + (size_t)r * SP_ + t0n + sc8);
            }
        }

        // ---- per m-block: S^T, exp, pack, PV (all in registers) ----
        #pragma unroll
        for (int iq = 0; iq < 2; ++iq) {
            floatx4 sacc[4] = {};
            #pragma unroll
            for (int ks = 0; ks < 2; ++ks)
                #pragma unroll
                for (int jb = 0; jb < 4; ++jb) {
                    bf16x8 kf = *(const bf16x8*)&Ks[(jb * 16 + lm) * AST + ks * 32 + lq * 8];
                    // SWAPPED: A=K rows (t), B=Q rows (q)  ->  C = S^T
                    sacc[jb] = __builtin_amdgcn_mfma_f32_16x16x32_bf16(
                        kf, af[iq][ks], sacc[jb], 0, 0, 0);
                }

            // lane (lm,lq): sacc[jb][r] = S[q][t_local = jb*16 + lq*4 + r]
            bf16x8 pf[2];   // [ks]: slots 0-3 = pb row 2ks, slots 4-7 = row 2ks+1
            if (!tail) {
                #pragma unroll
                for (int jb = 0; jb < 4; ++jb)
                    #pragma unroll
                    for (int r = 0; r < 4; ++r)
                        pf[jb >> 1][(jb & 1) * 4 + r] = (__bf16)exp2f(sacc[jb][r]);
            } else {
                #pragma unroll
                for (int jb = 0; jb < 4; ++jb)
                    #pragma unroll
                    for (int r = 0; r < 4; ++r) {
                        bool valid = (t0 + jb * 16 + lq * 4 + r) < S_;
                        pf[jb >> 1][(jb & 1) * 4 + r] =
                            valid ? (__bf16)exp2f(sacc[jb][r]) : (__bf16)0.f;
                    }
            }

            // PV per ks-half + ones-MFMA row-sum
            #pragma unroll
            for (int ks = 0; ks < 2; ++ks) {
                #pragma unroll
                for (int jb = 0; jb < 4; ++jb) {
                    bf16x8 bvf = *(const bf16x8*)&Vt[(jb * 16 + lm) * AST + ks * 32 + lq * 8];
                    oacc[iq][jb] = __builtin_amdgcn_mfma_f32_16x16x32_bf16(
                        pf[ks], bvf, oacc[iq][jb], 0, 0, 0);
                }
                lacc[iq] = __builtin_amdgcn_mfma_f32_16x16x32_bf16(
                    pf[ks], ones8, lacc[iq], 0, 0, 0);
            }
        }
    }

    // ---- epilogue: linv straight from lacc (row = lq*4+r matches output) ----
    #pragma unroll
    for (int iq = 0; iq < 2; ++iq) {
        float linv[4];
        #pragma unroll
        for (int r = 0; r < 4; ++r)
            linv[r] = 1.f / lacc[iq][r];
        #pragma unroll
        for (int jb = 0; jb < 4; ++jb)
            #pragma unroll
            for (int r = 0; r < 4; ++r) {
                int srow = qt * 128 + wave * 32 + iq * 16 + lq * 4 + r;
                if (srow < S_)
                    ctx[headbase + (size_t)srow * D_ + jb * 16 + lm] =
                        (__bf16)(oacc[iq][jb][r] * linv[r]);
            }
    }
}

// ---------------- fused residual + layernorm v2 ----------------
// 1 barrier (was ~16): fused sum+sumsq wave shfl-reduce -> 4 partials -> LDS.
// Vectorized: thread t owns elems 2t, 2t+1 (float2 / ushort2 / packed uint).
__global__ __launch_bounds__(256) void ln_kernel(
    const float* __restrict__ x, const __bf16* __restrict__ delta,
    const float* __restrict__ g, const float* __restrict__ b,
    float* __restrict__ out, __bf16* __restrict__ outb, int has_delta)
{
    int row = blockIdx.x;
    int tid = threadIdx.x;
    int wave = tid >> 6, lane = tid & 63;
    __shared__ float psum[4], psq[4];

    const size_t base = (size_t)row * D_;
    float2 v = *(const float2*)&x[base + tid * 2];
    float v0 = v.x, v1 = v.y;
    if (has_delta) {
        ushort2 dd = *(const ushort2*)&delta[base + tid * 2];
        union { unsigned short u; __bf16 h; } c0, c1;
        c0.u = dd.x; c1.u = dd.y;
        v0 += (float)c0.h;
        v1 += (float)c1.h;
    }
    float s = v0 + v1;
    float sq = v0 * v0 + v1 * v1;
    #pragma unroll
    for (int o = 1; o < 64; o <<= 1) {
        s  += __shfl_xor(s,  o, 64);
        sq += __shfl_xor(sq, o, 64);
    }
    if (lane == 0) { psum[wave] = s; psq[wave] = sq; }
    __syncthreads();
    float ts = psum[0] + psum[1] + psum[2] + psum[3];
    float tq = psq[0]  + psq[1]  + psq[2]  + psq[3];
    float mean = ts * (1.f / D_);
    float var  = tq * (1.f / D_) - mean * mean;
    float rstd = rsqrtf(var + 1e-5f);

    float2 gg = *(const float2*)&g[tid * 2];
    float2 bb = *(const float2*)&b[tid * 2];
    float o0 = (v0 - mean) * rstd * gg.x + bb.x;
    float o1 = (v1 - mean) * rstd * gg.y + bb.y;
    *(float2*)&out[base + tid * 2] = make_float2(o0, o1);
    union { unsigned short u[2]; unsigned int w; } pk;
    union { __bf16 h; unsigned short u; } h0, h1;
    h0.h = (__bf16)o0; h1.h = (__bf16)o1;
    pk.u[0] = h0.u; pk.u[1] = h1.u;
    *(unsigned int*)&outb[base + tid * 2] = pk.w;
}

// ---------------- anomaly head final ----------------
__global__ __launch_bounds__(256) void a2_kernel(
    const float* __restrict__ a1, const float* __restrict__ Wa2,
    const float* __restrict__ ba2, float* __restrict__ out)
{
    int row = blockIdx.x * 4 + (threadIdx.x >> 6);
    int lane = threadIdx.x & 63;
    if (row >= M_) return;
    float p = a1[(size_t)row * 64 + lane] * Wa2[lane];
    for (int o = 32; o > 0; o >>= 1) p += __shfl_down(p, o, 64);
    if (lane == 0) out[row] = 1.f / (1.f + expf(-(p + ba2[0])));
}

// ---------------- host launch ----------------
extern "C" void kernel_launch(void* const* d_in, const int* in_sizes, int n_in,
                              void* d_out, int out_size, void* d_ws, size_t ws_size,
                              hipStream_t stream)
{
    const float* x     = (const float*)d_in[0];
    const float* Win   = (const float*)d_in[1];
    const float* b_in  = (const float*)d_in[2];
    const float* Wq    = (const float*)d_in[3];
    const float* bq    = (const float*)d_in[4];
    const float* Wk    = (const float*)d_in[5];
    const float* bk    = (const float*)d_in[6];
    const float* Wv    = (const float*)d_in[7];
    const float* bv    = (const float*)d_in[8];
    const float* Wo    = (const float*)d_in[9];
    const float* bo    = (const float*)d_in[10];
    const float* W1    = (const float*)d_in[11];
    const float* b1    = (const float*)d_in[12];
    const float* W2    = (const float*)d_in[13];
    const float* b2    = (const float*)d_in[14];
    const float* ln1_g = (const float*)d_in[15];
    const float* ln1_b = (const float*)d_in[16];
    const float* ln2_g = (const float*)d_in[17];
    const float* ln2_b = (const float*)d_in[18];
    const float* lnf_g = (const float*)d_in[19];
    const float* lnf_b = (const float*)d_in[20];
    const float* Wf1   = (const float*)d_in[21];
    const float* bf1   = (const float*)d_in[22];
    const float* Wf2   = (const float*)d_in[23];
    const float* bf2   = (const float*)d_in[24];
    const float* Wr1   = (const float*)d_in[25];
    const float* br1   = (const float*)d_in[26];
    const float* Wr2   = (const float*)d_in[27];
    const float* br2   = (const float*)d_in[28];
    const float* Wr3   = (const float*)d_in[29];
    const float* br3   = (const float*)d_in[30];
    const float* Wa1   = (const float*)d_in[31];
    const float* ba1   = (const float*)d_in[32];
    const float* Wa2   = (const float*)d_in[33];
    const float* ba2   = (const float*)d_in[34];

    float* recon_out   = (float*)d_out;                     // [16000, 32]
    float* anomaly_out = (float*)d_out + (size_t)M_ * IN_;  // [16000, 1]

    // ---------- workspace layout (byte offsets) ----------
    char* ws = (char*)d_ws;
    float*  h    = (float*)(ws + 0);                 // 32,768,000 B
    __bf16* tmpb = (__bf16*)(ws + 32768000);         // 16,384,000 B
    __bf16* hb   = (__bf16*)(ws + 65536000);         // 16,384,000 B
    __bf16* qb   = (__bf16*)(ws + 81920000);         // 16,384,000 B  (kb = qb+8192000 el, vtb = qb+16384000 el)
    __bf16* kb   = (__bf16*)(ws + 98304000);         // 16,384,000 B
    __bf16* vtb  = (__bf16*)(ws + 114688000);        // 16,777,216 B ([B*H][64][SP_])
    __bf16* ctxb = (__bf16*)(ws + 131465216);        // 16,384,000 B (ends 147,849,216)
    __bf16* ffmid = qb;                              // 65,536,000 B (overlaps qb..ctxb start)

    // head temps (reuse region after encoder)
    __bf16* t1b   = (__bf16*)(ws + 81920000);        // 8,192,000 B
    __bf16* featb = (__bf16*)(ws + 90112000);        // 4,096,000 B
    __bf16* r1b   = (__bf16*)(ws + 94208000);        // 8,192,000 B
    __bf16* r2b   = (__bf16*)(ws + 102400000);       // 16,384,000 B
    float*  a1b   = (float*)(ws + 118784000);        // 4,096,000 B

    // bf16 transposed weights
    size_t woff = 147849216;
    auto alloc_bf = [&](size_t elems) { __bf16* p = (__bf16*)(ws + woff); woff += elems * 2; return p; };
    __bf16* WinT  = alloc_bf(32 * 512);
    __bf16* WqkvT = alloc_bf((size_t)L_ * 1536 * 512);   // [L][1536][512]
    __bf16* WoT   = alloc_bf((size_t)L_ * 512 * 512);
    __bf16* W1T   = alloc_bf((size_t)L_ * 512 * 2048);
    __bf16* W2T   = alloc_bf((size_t)L_ * 2048 * 512);
    __bf16* Wf1T  = alloc_bf(512 * 256);
    __bf16* Wf2T  = alloc_bf(256 * 128);
    __bf16* Wr1T  = alloc_bf(128 * 256);
    __bf16* Wr2T  = alloc_bf(256 * 512);
    __bf16* Wr3T  = alloc_bf(512 * 32);
    __bf16* Wa1T  = alloc_bf(128 * 64);
    __bf16* xb    = alloc_bf((size_t)M_ * IN_);
    float*  bqkv  = (float*)(ws + woff);  woff += (size_t)L_ * 1536 * 4;

    dim3 blk(256);
    auto gg = [](int N) { return dim3((N + 127) / 128, M_ / 128); };

    // ---------- weight prep (3 merged transpose launches) ----------
    hipLaunchKernelGGL(transpose_qkvo, dim3(16, 16, L_ * 4), blk, 0, stream,
                       Wq, Wk, Wv, Wo, WqkvT, WoT);
    hipLaunchKernelGGL(transpose_ffn, dim3(64, 64, L_ * 2), blk, 0, stream,
                       W1, W2, W1T, W2T);
    TDescArr misc;
    misc.d[0] = {Win, WinT, 32, 512, 1.f};
    misc.d[1] = {Wf1, Wf1T, 512, 256, 1.f};
    misc.d[2] = {Wf2, Wf2T, 256, 128, 1.f};
    misc.d[3] = {Wr1, Wr1T, 128, 256, 1.f};
    misc.d[4] = {Wr2, Wr2T, 256, 512, 1.f};
    misc.d[5] = {Wr3, Wr3T, 512, 32, 1.f};
    misc.d[6] = {Wa1, Wa1T, 128, 64, 1.f};
    hipLaunchKernelGGL(transpose_misc, dim3(16, 16, 7), blk, 0, stream, misc);
    hipLaunchKernelGGL(cast_bf16, dim3((M_ * IN_ + 255) / 256), blk, 0, stream,
                       x, xb, M_ * IN_);
    hipLaunchKernelGGL(concat_bias, dim3((L_ * 1536 + 255) / 256), blk, 0, stream,
                       bq, bk, bv, bqkv);

    // ---------- input projection + positional encoding ----------
    hipLaunchKernelGGL(gemm_mfma, gg(D_), blk, 0, stream,
                       xb, WinT, b_in, (void*)h, M_, D_, IN_, 0);
    hipLaunchKernelGGL(add_pos_kernel, dim3((B_ * S_ * D_ + 255) / 256), blk, 0, stream,
                       h, hb);

    // ---------- encoder layers ----------
    for (int l = 0; l < L_; ++l) {
        size_t wo = (size_t)l * 512 * 512;
        size_t fo = (size_t)l * 512 * 2048;

        hipLaunchKernelGGL(gemm_mfma, dim3(12, M_ / 128), blk, 0, stream,
                           hb, WqkvT + (size_t)l * 1536 * 512, bqkv + (size_t)l * 1536,
                           (void*)qb, M_, 1536, 512, FLAG_QKV);

        hipLaunchKernelGGL(attn_mfma, dim3(1024), blk, 0, stream,
                           qb, kb, vtb, ctxb);

        hipLaunchKernelGGL(gemm_mfma, gg(D_), blk, 0, stream,
                           ctxb, WoT + wo, bo + (size_t)l * D_, (void*)tmpb, M_, D_, D_,
                           FLAG_BF16);
        hipLaunchKernelGGL(ln_kernel, dim3(M_), blk, 0, stream,
                           h, tmpb, ln1_g + (size_t)l * D_, ln1_b + (size_t)l * D_, h, hb, 1);

        hipLaunchKernelGGL(gemm_mfma, gg(FF_), blk, 0, stream,
                           hb, W1T + fo, b1 + (size_t)l * FF_, (void*)ffmid, M_, FF_, D_,
                           FLAG_RELU | FLAG_BF16);
        hipLaunchKernelGGL(gemm_mfma, gg(D_), blk, 0, stream,
                           ffmid, W2T + fo, b2 + (size_t)l * D_, (void*)tmpb, M_, D_, FF_,
                           FLAG_BF16);
        hipLaunchKernelGGL(ln_kernel, dim3(M_), blk, 0, stream,
                           h, tmpb, ln2_g + (size_t)l * D_, ln2_b + (size_t)l * D_, h, hb, 1);
    }

    // final norm
    hipLaunchKernelGGL(ln_kernel, dim3(M_), blk, 0, stream,
                       h, nullptr, lnf_g, lnf_b, h, hb, 0);

    // ---------- heads ----------
    hipLaunchKernelGGL(gemm_mfma, gg(256), blk, 0, stream,
                       hb, Wf1T, bf1, (void*)t1b, M_, 256, 512, FLAG_RELU | FLAG_BF16);
    hipLaunchKernelGGL(gemm_mfma, gg(128), blk, 0, stream,
                       t1b, Wf2T, bf2, (void*)featb, M_, 128, 256, FLAG_BF16);

    hipLaunchKernelGGL(gemm_mfma, gg(256), blk, 0, stream,
                       featb, Wr1T, br1, (void*)r1b, M_, 256, 128, FLAG_RELU | FLAG_BF16);
    hipLaunchKernelGGL(gemm_mfma, gg(512), blk, 0, stream,
                       r1b, Wr2T, br2, (void*)r2b, M_, 512, 256, FLAG_RELU | FLAG_BF16);
    hipLaunchKernelGGL(gemm_mfma, gg(IN_), blk, 0, stream,
                       r2b, Wr3T, br3, (void*)recon_out, M_, IN_, 512, 0);

    hipLaunchKernelGGL(gemm_mfma, gg(64), blk, 0, stream,
                       featb, Wa1T, ba1, (void*)a1b, M_, 64, 128, FLAG_RELU);
    hipLaunchKernelGGL(a2_kernel, dim3((M_ + 3) / 4), blk, 0, stream,
                       a1b, Wa2, ba2, anomaly_out);
}

// Round 12
// 1870.771 us; speedup vs baseline: 1.0301x; 1.0301x over previous
//
#include <hip/hip_runtime.h>
#include <hip/hip_bf16.h>
#include <math.h>

// Problem constants
#define B_  16
#define S_  1000
#define IN_ 32
#define D_  512
#define H_  8
#define FF_ 2048
#define L_  6
#define DK_ 64
#define M_  (B_ * S_)   // 16000 rows
#define SP_ 1024        // padded sequence stride for V^T

typedef __bf16 bf16x8 __attribute__((ext_vector_type(8)));
typedef float  floatx4 __attribute__((ext_vector_type(4)));

#define FLAG_RELU 1
#define FLAG_BF16 2
#define FLAG_QKV  4

// softmax scale folded into Wq/bq at prep: 0.125 * log2(e)
#define QSCALE 0.18033688011112042f

// ============ bf16 MFMA GEMM: C[M,N] = act(A[M,K] @ B[K,N] + bias) ============
// A: bf16 [M][K] row-major. BT: bf16 [N][K] row-major. 128x128 tile, BK=32,
// 256 threads = 4 waves (64x64/wave via 4x4 of 16x16x32 MFMA).
// v14 = v10 exactly (session best, 1871us): 1-deep reg-prefetch + dbuf LDS +
// bijective XCD swizzle, unpadded 32-elem LDS rows, UNswapped MFMA operands.
// (v13's operand swap vectorized stores but perturbed K-loop codegen:
// VGPR 88->108, FF1 65->72us. v11's pad doubled conflicts. Both reverted.)
// FLAG_QKV: N=1536; epilogue routes n<512 -> q, <1024 -> k, else transposed V^T.
__global__ __launch_bounds__(256) void gemm_mfma(
    const __bf16* __restrict__ A, const __bf16* __restrict__ BT,
    const float* __restrict__ bias, void* __restrict__ C,
    int M, int N, int K, int flags)
{
    __shared__ __bf16 Asm[2][128 * 32];
    __shared__ __bf16 Bsm[2][128 * 32];

    int tid  = threadIdx.x;
    int wave = tid >> 6;
    int lane = tid & 63;

    // bijective chunked XCD swizzle (m204): orig%8 ~ hardware XCD; give each
    // XCD a contiguous chunk of the x-fastest linear id so same-row blocks
    // (sharing the A-panel) land on one XCD's L2.
    int gx = gridDim.x, nwg = gx * (int)gridDim.y;
    int orig = blockIdx.y * gx + blockIdx.x;
    int qq = nwg >> 3, rr = nwg & 7;
    int xcd = orig & 7, loc = orig >> 3;
    int nid = (xcd < rr ? xcd * (qq + 1) : rr * (qq + 1) + (xcd - rr) * qq) + loc;
    int bm = (nid / gx) * 128;
    int bn = (nid % gx) * 128;

    int wm = (wave & 1) * 64;
    int wn = (wave >> 1) * 64;
    int lm = lane & 15;
    int lq = lane >> 4;

    floatx4 acc[4][4] = {};

    // staging geometry: thread stages A/B rows crow, crow+64, 16B chunk cpart
    int crow  = tid >> 2;
    int cpart = (tid & 3) * 8;
    const __bf16* ag0 = A + (size_t)(bm + crow) * K + cpart;
    const __bf16* ag1 = A + (size_t)(bm + 64 + crow) * K + cpart;
    int nr0 = bn + crow, nr1 = bn + 64 + crow;
    const __bf16* bg0 = BT + (size_t)nr0 * K + cpart;
    const __bf16* bg1 = BT + (size_t)nr1 * K + cpart;
    bool bv0 = nr0 < N, bv1 = nr1 < N;

    // ---- prologue: load tile 0 into prefetch regs ----
    uint4 pa0, pa1, pb0, pb1;
    pa0 = *(const uint4*)ag0;
    pa1 = *(const uint4*)ag1;
    pb0 = bv0 ? *(const uint4*)bg0 : make_uint4(0, 0, 0, 0);
    pb1 = bv1 ? *(const uint4*)bg1 : make_uint4(0, 0, 0, 0);

    for (int k0 = 0, it = 0; k0 < K; k0 += 32, ++it) {
        const int cur = it & 1;
        // write prefetched tile (readers of this buffer finished before the
        // previous barrier -> single-barrier double-buffer is race-free)
        *(uint4*)&Asm[cur][tid * 8]        = pa0;
        *(uint4*)&Asm[cur][2048 + tid * 8] = pa1;
        *(uint4*)&Bsm[cur][tid * 8]        = pb0;
        *(uint4*)&Bsm[cur][2048 + tid * 8] = pb1;
        __syncthreads();

        // issue next tile's loads; they fly during compute below
        if (k0 + 32 < K) {
            pa0 = *(const uint4*)(ag0 + k0 + 32);
            pa1 = *(const uint4*)(ag1 + k0 + 32);
            pb0 = bv0 ? *(const uint4*)(bg0 + k0 + 32) : make_uint4(0, 0, 0, 0);
            pb1 = bv1 ? *(const uint4*)(bg1 + k0 + 32) : make_uint4(0, 0, 0, 0);
        }

        bf16x8 af[4], bf[4];
        #pragma unroll
        for (int i = 0; i < 4; ++i) {
            af[i] = *(const bf16x8*)&Asm[cur][(wm + i * 16 + lm) * 32 + lq * 8];
            bf[i] = *(const bf16x8*)&Bsm[cur][(wn + i * 16 + lm) * 32 + lq * 8];
        }
        #pragma unroll
        for (int i = 0; i < 4; ++i)
            #pragma unroll
            for (int j = 0; j < 4; ++j)
                acc[i][j] = __builtin_amdgcn_mfma_f32_16x16x32_bf16(
                    af[i], bf[j], acc[i][j], 0, 0, 0);
    }

    if (flags & FLAG_QKV) {
        int sec = bn >> 9;
        if (sec < 2) {
            __bf16* dst = (__bf16*)C + (sec ? (size_t)8192000 : 0);
            #pragma unroll
            for (int j = 0; j < 4; ++j) {
                int col = (bn & 511) + wn + j * 16 + lm;
                float bvv = bias[bn + wn + j * 16 + lm];
                #pragma unroll
                for (int i = 0; i < 4; ++i)
                    #pragma unroll
                    for (int r = 0; r < 4; ++r) {
                        int m = bm + wm + i * 16 + lq * 4 + r;
                        dst[(size_t)m * 512 + col] = (__bf16)(acc[i][j][r] + bvv);
                    }
            }
        } else {
            __bf16* vt = (__bf16*)C + (size_t)16384000;
            int bbq[4], s0[4];
            #pragma unroll
            for (int i = 0; i < 4; ++i) {
                int m0 = bm + wm + i * 16 + lq * 4;   // mult of 4; 1000%4==0
                bbq[i] = m0 / 1000;
                s0[i]  = m0 - bbq[i] * 1000;
            }
            #pragma unroll
            for (int j = 0; j < 4; ++j) {
                int col = (bn & 511) + wn + j * 16 + lm;
                float bvv = bias[bn + wn + j * 16 + lm];
                int head = col >> 6, dk = col & 63;
                #pragma unroll
                for (int i = 0; i < 4; ++i) {
                    __bf16 t4[4];
                    #pragma unroll
                    for (int r = 0; r < 4; ++r) t4[r] = (__bf16)(acc[i][j][r] + bvv);
                    *(uint2*)(vt + ((size_t)(bbq[i] * H_ + head) * DK_ + dk) * SP_ + s0[i])
                        = *(uint2*)t4;
                }
            }
        }
        return;
    }

    #pragma unroll
    for (int j = 0; j < 4; ++j) {
        int n = bn + wn + j * 16 + lm;
        if (n >= N) continue;
        float bv = bias[n];
        #pragma unroll
        for (int i = 0; i < 4; ++i) {
            #pragma unroll
            for (int r = 0; r < 4; ++r) {
                int m = bm + wm + i * 16 + lq * 4 + r;
                float v = acc[i][j][r] + bv;
                if (flags & FLAG_RELU) v = fmaxf(v, 0.f);
                if (flags & FLAG_BF16) ((__bf16*)C)[(size_t)m * N + n] = (__bf16)v;
                else                   ((float*)C)[(size_t)m * N + n] = v;
            }
        }
    }
}

// ---------------- shared 32x32 transpose helper ----------------
__device__ __forceinline__ void trans_tile(
    const float* __restrict__ src, __bf16* __restrict__ dst,
    int K, int N, float scale, int tx0, int ty0)
{
    __shared__ float t[32][33];
    int n0 = tx0 * 32, k0 = ty0 * 32;
    int tx = threadIdx.x & 31, ty = threadIdx.x >> 5;   // 32 x 8
    #pragma unroll
    for (int i = 0; i < 32; i += 8) {
        int k = k0 + ty + i, n = n0 + tx;
        t[ty + i][tx] = (k < K && n < N) ? src[(size_t)k * N + n] * scale : 0.f;
    }
    __syncthreads();
    #pragma unroll
    for (int i = 0; i < 32; i += 8) {
        int n = n0 + ty + i, k = k0 + tx;
        if (n < N && k < K) dst[(size_t)n * K + k] = (__bf16)t[tx][ty + i];
    }
}

// ---- merged QKVO weight prep: z = l*4 + {0:q,1:k,2:v,3:o}, all 512x512 ----
__global__ __launch_bounds__(256) void transpose_qkvo(
    const float* __restrict__ Wq, const float* __restrict__ Wk,
    const float* __restrict__ Wv, const float* __restrict__ Wo,
    __bf16* __restrict__ WqkvT, __bf16* __restrict__ WoT)
{
    int l = blockIdx.z >> 2, which = blockIdx.z & 3;
    const float* src; __bf16* dst; float sc = 1.f;
    size_t so = (size_t)l * 512 * 512;
    if (which == 0)      { src = Wq + so; dst = WqkvT + (size_t)l * 1536 * 512; sc = QSCALE; }
    else if (which == 1) { src = Wk + so; dst = WqkvT + (size_t)l * 1536 * 512 + 512 * 512; }
    else if (which == 2) { src = Wv + so; dst = WqkvT + (size_t)l * 1536 * 512 + 1024 * 512; }
    else                 { src = Wo + so; dst = WoT + so; }
    trans_tile(src, dst, 512, 512, sc, blockIdx.x, blockIdx.y);
}

// ---- merged FFN weight prep: z = l*2 + {0:W1 (512x2048), 1:W2 (2048x512)} ----
__global__ __launch_bounds__(256) void transpose_ffn(
    const float* __restrict__ W1, const float* __restrict__ W2,
    __bf16* __restrict__ W1T, __bf16* __restrict__ W2T)
{
    int l = blockIdx.z >> 1, which = blockIdx.z & 1;
    size_t so = (size_t)l * 512 * 2048;
    int K = which ? 2048 : 512, N = which ? 512 : 2048;
    if ((int)blockIdx.x >= N / 32 || (int)blockIdx.y >= K / 32) return;
    trans_tile((which ? W2 : W1) + so, (which ? W2T : W1T) + so,
               K, N, 1.f, blockIdx.x, blockIdx.y);
}

// ---- merged misc weight prep via descriptor array ----
struct TDesc { const float* src; __bf16* dst; int K; int N; float scale; };
struct TDescArr { TDesc d[7]; };

__global__ __launch_bounds__(256) void transpose_misc(TDescArr ds)
{
    TDesc t = ds.d[blockIdx.z];
    if ((int)blockIdx.x * 32 >= t.N || (int)blockIdx.y * 32 >= t.K) return;
    trans_tile(t.src, t.dst, t.K, t.N, t.scale, blockIdx.x, blockIdx.y);
}

// ---------------- fp32 -> bf16 cast ----------------
__global__ void cast_bf16(const float* __restrict__ src, __bf16* __restrict__ dst, int n)
{
    int i = blockIdx.x * 256 + threadIdx.x;
    if (i < n) dst[i] = (__bf16)src[i];
}

// ---------------- concat q/k/v biases into [L][1536]; bq scaled ----------------
__global__ void concat_bias(const float* __restrict__ bq, const float* __restrict__ bk,
                            const float* __restrict__ bv, float* __restrict__ dst)
{
    int i = blockIdx.x * 256 + threadIdx.x;
    if (i >= L_ * 1536) return;
    int l = i / 1536, j = i - l * 1536;
    float v = (j < 512) ? bq[l * 512 + j] * QSCALE
            : (j < 1024) ? bk[l * 512 + j - 512]
                         : bv[l * 512 + j - 1024];
    dst[i] = v;
}

// ---------------- positional encoding add (writes fp32 + bf16) ----------------
__global__ void add_pos_kernel(float* __restrict__ h, __bf16* __restrict__ hb)
{
    int idx = blockIdx.x * 256 + threadIdx.x;
    if (idx >= B_ * S_ * D_) return;
    int d = idx % D_;
    int s = (idx / D_) % S_;
    int two_i = d & ~1;
    float ang = (float)s * expf((float)two_i * (-9.210340371976184f / (float)D_));
    float v = h[idx] + ((d & 1) ? cosf(ang) : sinf(ang));
    h[idx] = v;
    hb[idx] = (__bf16)v;
}

// ============ MFMA flash attention v7 (unchanged from round 5's best) ============
#define AST 72   // LDS row stride in bf16 (144 B, 16B-aligned)

__global__ __launch_bounds__(256) void attn_mfma(
    const __bf16* __restrict__ q, const __bf16* __restrict__ k,
    const __bf16* __restrict__ vt, __bf16* __restrict__ ctx)
{
    // chunked XCD swizzle over 1024 blocks (1024 % 8 == 0 -> bijective)
    const int id = blockIdx.x;
    const int w  = (id & 7) * 128 + (id >> 3);
    const int qt = w & 7, hh = (w >> 3) & 7, bb = w >> 6;

    const int tid = threadIdx.x;
    const int wave = tid >> 6, lane = tid & 63;
    const int lm = lane & 15, lq = lane >> 4;

    __shared__ __bf16 Ks[64 * AST];
    __shared__ __bf16 Vt[64 * AST];

    const size_t headbase = (size_t)bb * S_ * D_ + hh * DK_;
    const __bf16* kbase  = k + headbase;
    const __bf16* vtbase = vt + (size_t)(bb * H_ + hh) * DK_ * SP_;

    // ---- Q fragments straight from global (B operand of swapped QK^T) ----
    bf16x8 af[2][2] = {};
    #pragma unroll
    for (int iq = 0; iq < 2; ++iq) {
        int qrow = qt * 128 + wave * 32 + iq * 16 + lm;
        if (qrow < S_) {
            const __bf16* qp = q + headbase + (size_t)qrow * D_;
            af[iq][0] = *(const bf16x8*)(qp + lq * 8);
            af[iq][1] = *(const bf16x8*)(qp + 32 + lq * 8);
        }
    }

    floatx4 oacc[2][4] = {};
    floatx4 lacc[2] = {};          // row-sum accumulators via ones-MFMA

    bf16x8 ones8;
    #pragma unroll
    for (int j = 0; j < 8; ++j) ones8[j] = (__bf16)1.f;

    // staging geometry (invariant): thread stages rows sr, sr+32, 16B chunk sc8
    const int sr  = tid >> 3;
    const int sc8 = (tid & 7) * 8;
    // inverse bit-permutation for V columns: group base T -> LDS col
    // c = T5*32 + T3*16 + T2*8 + T4*4   (low 2 bits pass through)
    const int colA = (sc8 & 32) | ((sc8 & 8) << 1) | ((sc8 & 16) >> 2);

    // ---- prologue: load tile 0 into regs ----
    uint4 ku[2], vu[2];
    #pragma unroll
    for (int i = 0; i < 2; ++i) {
        int r = sr + i * 32;
        ku[i] = *(const uint4*)(kbase + (size_t)r * D_ + sc8);
        vu[i] = *(const uint4*)(vtbase + (size_t)r * SP_ + sc8);
    }

    for (int jt = 0; jt < 16; ++jt) {
        const int t0 = jt * 64;
        const bool tail = (jt == 15);

        __syncthreads();   // all waves done reading Ks/Vt of previous tile
        #pragma unroll
        for (int i = 0; i < 2; ++i) {
            int r = sr + i * 32;
            *(uint4*)&Ks[r * AST + sc8] = ku[i];
            uint2 vlo = make_uint2(vu[i].x, vu[i].y);   // t_local sc8..sc8+3
            uint2 vhi = make_uint2(vu[i].z, vu[i].w);   // t_local sc8+4..sc8+7
            *(uint2*)&Vt[r * AST + colA]     = vlo;
            *(uint2*)&Vt[r * AST + colA + 8] = vhi;
        }
        __syncthreads();

        // ---- issue next tile's loads; they fly during compute below ----
        if (jt < 15) {
            int t0n = t0 + 64;
            #pragma unroll
            for (int i = 0; i < 2; ++i) {
                int r = sr + i * 32;
                int trow = t0n + r;
                ku[i] = (trow < S_) ? *(const uint4*)(kbase + (size_t)trow * D_ + sc8)
                                    : make_uint4(0, 0, 0, 0);
                vu[i] = *(const uint4*)(vtbase + (size_t)r * SP_ + t0n + sc8);
            }
        }

        // ---- per m-block: S^T, exp, pack, PV (all in registers) ----
        #pragma unroll
        for (int iq = 0; iq < 2; ++iq) {
            floatx4 sacc[4] = {};
            #pragma unroll
            for (int ks = 0; ks < 2; ++ks)
                #pragma unroll
                for (int jb = 0; jb < 4; ++jb) {
                    bf16x8 kf = *(const bf16x8*)&Ks[(jb * 16 + lm) * AST + ks * 32 + lq * 8];
                    // SWAPPED: A=K rows (t), B=Q rows (q)  ->  C = S^T
                    sacc[jb] = __builtin_amdgcn_mfma_f32_16x16x32_bf16(
                        kf, af[iq][ks], sacc[jb], 0, 0, 0);
                }

            // lane (lm,lq): sacc[jb][r] = S[q][t_local = jb*16 + lq*4 + r]
            bf16x8 pf[2];   // [ks]: slots 0-3 = pb row 2ks, slots 4-7 = row 2ks+1
            if (!tail) {
                #pragma unroll
                for (int jb = 0; jb < 4; ++jb)
                    #pragma unroll
                    for (int r = 0; r < 4; ++r)
                        pf[jb >> 1][(jb & 1) * 4 + r] = (__bf16)exp2f(sacc[jb][r]);
            } else {
                #pragma unroll
                for (int jb = 0; jb < 4; ++jb)
                    #pragma unroll
                    for (int r = 0; r < 4; ++r) {
                        bool valid = (t0 + jb * 16 + lq * 4 + r) < S_;
                        pf[jb >> 1][(jb & 1) * 4 + r] =
                            valid ? (__bf16)exp2f(sacc[jb][r]) : (__bf16)0.f;
                    }
            }

            // PV per ks-half + ones-MFMA row-sum
            #pragma unroll
            for (int ks = 0; ks < 2; ++ks) {
                #pragma unroll
                for (int jb = 0; jb < 4; ++jb) {
                    bf16x8 bvf = *(const bf16x8*)&Vt[(jb * 16 + lm) * AST + ks * 32 + lq * 8];
                    oacc[iq][jb] = __builtin_amdgcn_mfma_f32_16x16x32_bf16(
                        pf[ks], bvf, oacc[iq][jb], 0, 0, 0);
                }
                lacc[iq] = __builtin_amdgcn_mfma_f32_16x16x32_bf16(
                    pf[ks], ones8, lacc[iq], 0, 0, 0);
            }
        }
    }

    // ---- epilogue: linv straight from lacc (row = lq*4+r matches output) ----
    #pragma unroll
    for (int iq = 0; iq < 2; ++iq) {
        float linv[4];
        #pragma unroll
        for (int r = 0; r < 4; ++r)
            linv[r] = 1.f / lacc[iq][r];
        #pragma unroll
        for (int jb = 0; jb < 4; ++jb)
            #pragma unroll
            for (int r = 0; r < 4; ++r) {
                int srow = qt * 128 + wave * 32 + iq * 16 + lq * 4 + r;
                if (srow < S_)
                    ctx[headbase + (size_t)srow * D_ + jb * 16 + lm] =
                        (__bf16)(oacc[iq][jb][r] * linv[r]);
            }
    }
}

// ---------------- fused residual + layernorm (delta bf16; writes fp32+bf16) ----
__global__ __launch_bounds__(256) void ln_kernel(
    const float* __restrict__ x, const __bf16* __restrict__ delta,
    const float* __restrict__ g, const float* __restrict__ b,
    float* __restrict__ out, __bf16* __restrict__ outb, int has_delta)
{
    int row = blockIdx.x;
    int tid = threadIdx.x;
    __shared__ float red[256];

    const size_t base = (size_t)row * D_;
    float v0 = x[base + tid];
    float v1 = x[base + tid + 256];
    if (has_delta) {
        v0 += (float)delta[base + tid];
        v1 += (float)delta[base + tid + 256];
    }
    red[tid] = v0 + v1; __syncthreads();
    for (int o = 128; o > 0; o >>= 1) {
        if (tid < o) red[tid] += red[tid + o];
        __syncthreads();
    }
    float mean = red[0] * (1.f / D_);
    __syncthreads();
    float d0 = v0 - mean, d1 = v1 - mean;
    red[tid] = d0 * d0 + d1 * d1; __syncthreads();
    for (int o = 128; o > 0; o >>= 1) {
        if (tid < o) red[tid] += red[tid + o];
        __syncthreads();
    }
    float rstd = rsqrtf(red[0] * (1.f / D_) + 1e-5f);
    float o0 = d0 * rstd * g[tid]       + b[tid];
    float o1 = d1 * rstd * g[tid + 256] + b[tid + 256];
    out[base + tid]        = o0;
    out[base + tid + 256]  = o1;
    outb[base + tid]       = (__bf16)o0;
    outb[base + tid + 256] = (__bf16)o1;
}

// ---------------- anomaly head final ----------------
__global__ __launch_bounds__(256) void a2_kernel(
    const float* __restrict__ a1, const float* __restrict__ Wa2,
    const float* __restrict__ ba2, float* __restrict__ out)
{
    int row = blockIdx.x * 4 + (threadIdx.x >> 6);
    int lane = threadIdx.x & 63;
    if (row >= M_) return;
    float p = a1[(size_t)row * 64 + lane] * Wa2[lane];
    for (int o = 32; o > 0; o >>= 1) p += __shfl_down(p, o, 64);
    if (lane == 0) out[row] = 1.f / (1.f + expf(-(p + ba2[0])));
}

// ---------------- host launch ----------------
extern "C" void kernel_launch(void* const* d_in, const int* in_sizes, int n_in,
                              void* d_out, int out_size, void* d_ws, size_t ws_size,
                              hipStream_t stream)
{
    const float* x     = (const float*)d_in[0];
    const float* Win   = (const float*)d_in[1];
    const float* b_in  = (const float*)d_in[2];
    const float* Wq    = (const float*)d_in[3];
    const float* bq    = (const float*)d_in[4];
    const float* Wk    = (const float*)d_in[5];
    const float* bk    = (const float*)d_in[6];
    const float* Wv    = (const float*)d_in[7];
    const float* bv    = (const float*)d_in[8];
    const float* Wo    = (const float*)d_in[9];
    const float* bo    = (const float*)d_in[10];
    const float* W1    = (const float*)d_in[11];
    const float* b1    = (const float*)d_in[12];
    const float* W2    = (const float*)d_in[13];
    const float* b2    = (const float*)d_in[14];
    const float* ln1_g = (const float*)d_in[15];
    const float* ln1_b = (const float*)d_in[16];
    const float* ln2_g = (const float*)d_in[17];
    const float* ln2_b = (const float*)d_in[18];
    const float* lnf_g = (const float*)d_in[19];
    const float* lnf_b = (const float*)d_in[20];
    const float* Wf1   = (const float*)d_in[21];
    const float* bf1   = (const float*)d_in[22];
    const float* Wf2   = (const float*)d_in[23];
    const float* bf2   = (const float*)d_in[24];
    const float* Wr1   = (const float*)d_in[25];
    const float* br1   = (const float*)d_in[26];
    const float* Wr2   = (const float*)d_in[27];
    const float* br2   = (const float*)d_in[28];
    const float* Wr3   = (const float*)d_in[29];
    const float* br3   = (const float*)d_in[30];
    const float* Wa1   = (const float*)d_in[31];
    const float* ba1   = (const float*)d_in[32];
    const float* Wa2   = (const float*)d_in[33];
    const float* ba2   = (const float*)d_in[34];

    float* recon_out   = (float*)d_out;                     // [16000, 32]
    float* anomaly_out = (float*)d_out + (size_t)M_ * IN_;  // [16000, 1]

    // ---------- workspace layout (byte offsets) ----------
    char* ws = (char*)d_ws;
    float*  h    = (float*)(ws + 0);                 // 32,768,000 B
    __bf16* tmpb = (__bf16*)(ws + 32768000);         // 16,384,000 B
    __bf16* hb   = (__bf16*)(ws + 65536000);         // 16,384,000 B
    __bf16* qb   = (__bf16*)(ws + 81920000);         // 16,384,000 B  (kb = qb+8192000 el, vtb = qb+16384000 el)
    __bf16* kb   = (__bf16*)(ws + 98304000);         // 16,384,000 B
    __bf16* vtb  = (__bf16*)(ws + 114688000);        // 16,777,216 B ([B*H][64][SP_])
    __bf16* ctxb = (__bf16*)(ws + 131465216);        // 16,384,000 B (ends 147,849,216)
    __bf16* ffmid = qb;                              // 65,536,000 B (overlaps qb..ctxb start)

    // head temps (reuse region after encoder)
    __bf16* t1b   = (__bf16*)(ws + 81920000);        // 8,192,000 B
    __bf16* featb = (__bf16*)(ws + 90112000);        // 4,096,000 B
    __bf16* r1b   = (__bf16*)(ws + 94208000);        // 8,192,000 B
    __bf16* r2b   = (__bf16*)(ws + 102400000);       // 16,384,000 B
    float*  a1b   = (float*)(ws + 118784000);        // 4,096,000 B

    // bf16 transposed weights
    size_t woff = 147849216;
    auto alloc_bf = [&](size_t elems) { __bf16* p = (__bf16*)(ws + woff); woff += elems * 2; return p; };
    __bf16* WinT  = alloc_bf(32 * 512);
    __bf16* WqkvT = alloc_bf((size_t)L_ * 1536 * 512);   // [L][1536][512]
    __bf16* WoT   = alloc_bf((size_t)L_ * 512 * 512);
    __bf16* W1T   = alloc_bf((size_t)L_ * 512 * 2048);
    __bf16* W2T   = alloc_bf((size_t)L_ * 2048 * 512);
    __bf16* Wf1T  = alloc_bf(512 * 256);
    __bf16* Wf2T  = alloc_bf(256 * 128);
    __bf16* Wr1T  = alloc_bf(128 * 256);
    __bf16* Wr2T  = alloc_bf(256 * 512);
    __bf16* Wr3T  = alloc_bf(512 * 32);
    __bf16* Wa1T  = alloc_bf(128 * 64);
    __bf16* xb    = alloc_bf((size_t)M_ * IN_);
    float*  bqkv  = (float*)(ws + woff);  woff += (size_t)L_ * 1536 * 4;

    dim3 blk(256);
    auto gg = [](int N) { return dim3((N + 127) / 128, M_ / 128); };

    // ---------- weight prep (3 merged transpose launches) ----------
    hipLaunchKernelGGL(transpose_qkvo, dim3(16, 16, L_ * 4), blk, 0, stream,
                       Wq, Wk, Wv, Wo, WqkvT, WoT);
    hipLaunchKernelGGL(transpose_ffn, dim3(64, 64, L_ * 2), blk, 0, stream,
                       W1, W2, W1T, W2T);
    TDescArr misc;
    misc.d[0] = {Win, WinT, 32, 512, 1.f};
    misc.d[1] = {Wf1, Wf1T, 512, 256, 1.f};
    misc.d[2] = {Wf2, Wf2T, 256, 128, 1.f};
    misc.d[3] = {Wr1, Wr1T, 128, 256, 1.f};
    misc.d[4] = {Wr2, Wr2T, 256, 512, 1.f};
    misc.d[5] = {Wr3, Wr3T, 512, 32, 1.f};
    misc.d[6] = {Wa1, Wa1T, 128, 64, 1.f};
    hipLaunchKernelGGL(transpose_misc, dim3(16, 16, 7), blk, 0, stream, misc);
    hipLaunchKernelGGL(cast_bf16, dim3((M_ * IN_ + 255) / 256), blk, 0, stream,
                       x, xb, M_ * IN_);
    hipLaunchKernelGGL(concat_bias, dim3((L_ * 1536 + 255) / 256), blk, 0, stream,
                       bq, bk, bv, bqkv);

    // ---------- input projection + positional encoding ----------
    hipLaunchKernelGGL(gemm_mfma, gg(D_), blk, 0, stream,
                       xb, WinT, b_in, (void*)h, M_, D_, IN_, 0);
    hipLaunchKernelGGL(add_pos_kernel, dim3((B_ * S_ * D_ + 255) / 256), blk, 0, stream,
                       h, hb);

    // ---------- encoder layers ----------
    for (int l = 0; l < L_; ++l) {
        size_t wo = (size_t)l * 512 * 512;
        size_t fo = (size_t)l * 512 * 2048;

        hipLaunchKernelGGL(gemm_mfma, dim3(12, M_ / 128), blk, 0, stream,
                           hb, WqkvT + (size_t)l * 1536 * 512, bqkv + (size_t)l * 1536,
                           (void*)qb, M_, 1536, 512, FLAG_QKV);

        hipLaunchKernelGGL(attn_mfma, dim3(1024), blk, 0, stream,
                           qb, kb, vtb, ctxb);

        hipLaunchKernelGGL(gemm_mfma, gg(D_), blk, 0, stream,
                           ctxb, WoT + wo, bo + (size_t)l * D_, (void*)tmpb, M_, D_, D_,
                           FLAG_BF16);
        hipLaunchKernelGGL(ln_kernel, dim3(M_), blk, 0, stream,
                           h, tmpb, ln1_g + (size_t)l * D_, ln1_b + (size_t)l * D_, h, hb, 1);

        hipLaunchKernelGGL(gemm_mfma, gg(FF_), blk, 0, stream,
                           hb, W1T + fo, b1 + (size_t)l * FF_, (void*)ffmid, M_, FF_, D_,
                           FLAG_RELU | FLAG_BF16);
        hipLaunchKernelGGL(gemm_mfma, gg(D_), blk, 0, stream,
                           ffmid, W2T + fo, b2 + (size_t)l * D_, (void*)tmpb, M_, D_, FF_,
                           FLAG_BF16);
        hipLaunchKernelGGL(ln_kernel, dim3(M_), blk, 0, stream,
                           h, tmpb, ln2_g + (size_t)l * D_, ln2_b + (size_t)l * D_, h, hb, 1);
    }

    // final norm
    hipLaunchKernelGGL(ln_kernel, dim3(M_), blk, 0, stream,
                       h, nullptr, lnf_g, lnf_b, h, hb, 0);

    // ---------- heads ----------
    hipLaunchKernelGGL(gemm_mfma, gg(256), blk, 0, stream,
                       hb, Wf1T, bf1, (void*)t1b, M_, 256, 512, FLAG_RELU | FLAG_BF16);
    hipLaunchKernelGGL(gemm_mfma, gg(128), blk, 0, stream,
                       t1b, Wf2T, bf2, (void*)featb, M_, 128, 256, FLAG_BF16);

    hipLaunchKernelGGL(gemm_mfma, gg(256), blk, 0, stream,
                       featb, Wr1T, br1, (void*)r1b, M_, 256, 128, FLAG_RELU | FLAG_BF16);
    hipLaunchKernelGGL(gemm_mfma, gg(512), blk, 0, stream,
                       r1b, Wr2T, br2, (void*)r2b, M_, 512, 256, FLAG_RELU | FLAG_BF16);
    hipLaunchKernelGGL(gemm_mfma, gg(IN_), blk, 0, stream,
                       r2b, Wr3T, br3, (void*)recon_out, M_, IN_, 512, 0);

    hipLaunchKernelGGL(gemm_mfma, gg(64), blk, 0, stream,
                       featb, Wa1T, ba1, (void*)a1b, M_, 64, 128, FLAG_RELU);
    hipLaunchKernelGGL(a2_kernel, dim3((M_ + 3) / 4), blk, 0, stream,
                       a1b, Wa2, ba2, anomaly_out);
}